// Round 7
// baseline (263.829 us; speedup 1.0000x reference)
//
#include <hip/hip_runtime.h>
#include <hip/hip_bf16.h>

// Problem constants (fixed by setup_inputs)
#define NXc 16384
#define DHc 128          // d_hidden
#define DLc 64           // d_latent
#define Kc  3            // neighbor radius
#define Wc  7            // 2k+1 offsets
#define Pc  32           // points per block
#define NTc 256          // threads per block
#define HALO 38          // Pc + 2*Kc
#define RB  272          // bf16 activation LDS row stride (128*2 + 16 pad)

typedef __attribute__((ext_vector_type(8))) short short8;   // 8 bf16 = one MFMA A/B fragment
typedef __attribute__((ext_vector_type(4))) float f32x4;    // MFMA accumulator
typedef __attribute__((ext_vector_type(2))) float f32x2;    // packed-fp32 pair

// LDS layout (bytes), double-aliased for 8 blocks/CU:
//   GN,S live B->C (reads).  HC aliases GN (written in C *after* an intra-C barrier).
//   H2 aliases S  (written in D, S dead after C's MFMA reads).
#define OFF_U  0                    // 38 fp32 (pad to 160)
#define OFF_X  160                  // -> 320
#define OFF_GN 320                  // bf16 [32][RB] = 8704 -> 9024
#define OFF_S  9024                 // bf16 [32][RB] = 8704 -> 17728
#define OFF_HC OFF_GN               // alias: written in C after barrier, read in D
#define OFF_H2 OFF_S                // alias: written in D, read in E
#define SMEM_BYTES 17728            // LDS allows 8 blocks/CU (8*17728 = 141824 <= 163840)

// LEDGER of measured facts:
// r2: __launch_bounds__(256,8) -> VGPR 32, spill, 252us. (256,6) is spill-free.
// r3: occupancy 6->8 blocks/CU bought only 127->123us => VALU-issue bound.
// r4: wholesale asm v_pk_* -> spill (0.78 GB), 234us.
// r5: native float2 poly: clean (VGPR 40, FETCH 5MB), 121us, VALU-busy 89.6us.
// r6: surgical asm v_pk_* Horner (packing FORCED) -> spill again (0.55 GB) BUT
//     VALU-busy 90.5us == r5's 89.6 => r5 was already packed; ~90us VALU issue is
//     the gelu-arithmetic floor (deg-8 packed ~= exp2 scalar in issue slots).
// r7 (this): r5 + cross-barrier weight prefetch. The only remaining attackable
//     time is ~30us of non-issue stall; phases C/D/E each start with 8-16 global
//     L2-latency loads the compiler cannot hoist across __syncthreads. Prefetch
//     kt=0 fragments one phase early by hand (plain loads, named regs, +16 VGPR).

// ws layout in bf16 elements. Fragment f=(nt*4+kt), lane l, j:
// element W[kt*32 + (l>>4)*8 + j][nt*16 + (l&15)] at base + f*512 + l*8 + j.
// Used as the MFMA *A* operand => D = (act@W)^T (register-transpose trick).
#define WS_NW2 0        // 128x64
#define WS_EW2 8192     // 128x64
#define WS_CW1 16384    // 128x128
#define WS_CW2 32768    // 128x64
#define WS_TOTAL 40960

#if __has_builtin(__builtin_amdgcn_exp2f)
#define EXP2F(x) __builtin_amdgcn_exp2f(x)
#else
#define EXP2F(x) exp2f(x)
#endif
#if __has_builtin(__builtin_amdgcn_rcpf)
#define RCPF(x) __builtin_amdgcn_rcpf(x)
#else
#define RCPF(x) (1.0f / (x))
#endif

// tanh-form GELU via sigmoid: gelu(x) = x / (1 + exp2(x*(c0 + c1*x^2)))
// Kept ONLY for phase D (args not analytically range-bounded).
#define GC0 -2.30220838f
#define GC1 -0.10294325f

__device__ __forceinline__ void gelu2(float x0, float x1, float& g0, float& g1) {
    x0 = fmaxf(x0, -8.0f);
    x1 = fmaxf(x1, -8.0f);
    float e0 = EXP2F(x0 * fmaf(GC1, x0 * x0, GC0));
    float e1 = EXP2F(x1 * fmaf(GC1, x1 * x1, GC0));
    float t0 = 1.0f + e0, t1 = 1.0f + e1;
    float rr = RCPF(t0 * t1);
    g0 = x0 * t1 * rr;
    g1 = x1 * t0 * rr;
}

// ---- packed exact-GELU polynomial (phase B), NATIVE vector form (r5-verified) ----
// gelu(x) = x*Phi(x); Phi(x) = 0.5 + x*T(z), z = x^2, T even & smooth.
// Degree-8 Newton interpolation of T through EXACT normal-CDF nodes
// x = {0,.5,1,1.5,2,2.5,3,3.25,3.5}; |gelu err| <= ~1e-4 for |x|<=3.5
// (accuracy harness-verified rounds 1/4/5/6: absmax identical to exp2 form).
#define PT0 0.39894230f
#define PT1 -0.066489615f
#define PT2 0.0099705784f
#define PT3 -0.0011833764f
#define PT4 1.1289751e-4f
#define PT5 -8.5460760e-6f
#define PT6 4.7818100e-7f
#define PT7 -1.7065000e-8f
#define PT8 2.8231000e-10f

#define SPL(c) ((f32x2){(c), (c)})

__device__ __forceinline__ f32x2 pf(f32x2 a, f32x2 b, f32x2 c) {
#if __has_builtin(__builtin_elementwise_fma)
    return __builtin_elementwise_fma(a, b, c);
#else
    return (f32x2){ fmaf(a.x, b.x, c.x), fmaf(a.y, b.y, c.y) };
#endif
}

// Phi(x) for a packed pair, z supplied by caller.
__device__ __forceinline__ f32x2 phi_pk(f32x2 x, f32x2 z) {
    f32x2 t = pf(SPL(PT8), z, SPL(PT7));
    t = pf(t, z, SPL(PT6));
    t = pf(t, z, SPL(PT5));
    t = pf(t, z, SPL(PT4));
    t = pf(t, z, SPL(PT3));
    t = pf(t, z, SPL(PT2));
    t = pf(t, z, SPL(PT1));
    t = pf(t, z, SPL(PT0));
    return pf(x, t, SPL(0.5f));   // Phi(x)
}
// node gelu: args analytically bounded |x| <= ~2.6 -> no clamp
__device__ __forceinline__ f32x2 gelu_pk(f32x2 x) {
    return x * phi_pk(x, x * x);
}
// edge gelu-accumulate: args bounded |x| <~ 3.4; z-clamp (2 scalar v_min, no packed
// f32 min exists) guards the fast-diverging extrapolation beyond 3.6.
__device__ __forceinline__ void gelu_pk_acc(f32x2 x, f32x2& acc) {
    f32x2 z = x * x;
    z.x = fminf(z.x, 12.96f);
    z.y = fminf(z.y, 12.96f);
    acc = pf(x, phi_pk(x, z), acc);
}

// bf16 pair pack: HW v_cvt_pk_bf16_f32 (gfx950) when available, else branchless RNE.
#if __has_builtin(__builtin_amdgcn_cvt_pk_bf16_f32)
typedef __attribute__((ext_vector_type(2))) __bf16 bf16x2_t;
__device__ __forceinline__ unsigned pack_bf16(float a, float b) {
    bf16x2_t v = __builtin_amdgcn_cvt_pk_bf16_f32(a, b);   // lo = src0, hi = src1
    unsigned r; __builtin_memcpy(&r, &v, 4); return r;
}
#else
__device__ __forceinline__ unsigned bf16rne(float a) {
    unsigned u;
    __builtin_memcpy(&u, &a, 4);
    return u + 0x7FFFu + ((u >> 16) & 1u);
}
__device__ __forceinline__ unsigned pack_bf16(float a, float b) {
    return (bf16rne(a) >> 16) | (bf16rne(b) & 0xFFFF0000u);
}
#endif
__device__ __forceinline__ void store_bf16x4(void* p, float a, float b, float c, float d) {
    uint2 u;
    u.x = pack_bf16(a, b);
    u.y = pack_bf16(c, d);
    *(uint2*)p = u;
}

// ---- prep: fp32 weights -> bf16 MFMA fragments in ws ----
__global__ void pack_weights(const float* __restrict__ nw2, const float* __restrict__ ew2,
                             const float* __restrict__ cw1, const float* __restrict__ cw2,
                             __hip_bfloat16* __restrict__ ws)
{
    int idx = blockIdx.x * 256 + threadIdx.x;     // 0 .. 40959
    const float* src;
    int N, base, e;
    if (idx < 8192)       { src = nw2; N = 64;  base = WS_NW2; e = idx; }
    else if (idx < 16384) { src = ew2; N = 64;  base = WS_EW2; e = idx - 8192; }
    else if (idx < 32768) { src = cw1; N = 128; base = WS_CW1; e = idx - 16384; }
    else                  { src = cw2; N = 64;  base = WS_CW2; e = idx - 32768; }
    int f = e >> 9, l = (e >> 3) & 63, j = e & 7;
    int nt = f >> 2, kt = f & 3;
    int k = kt * 32 + (l >> 4) * 8 + j;
    int n = nt * 16 + (l & 15);
    ws[base + e] = __float2bfloat16(src[k * N + n]);
}

__global__ __launch_bounds__(NTc, 6)
void lifting_mfma(const float* __restrict__ u0, const float* __restrict__ x,
                  const float* __restrict__ nw1, const float* __restrict__ nb1,
                  const float* __restrict__ nb2, const float* __restrict__ eb1,
                  const float* __restrict__ eb2, const float* __restrict__ cb1,
                  const float* __restrict__ cb2, const float* __restrict__ ew1,
                  const short8* __restrict__ wsv, float* __restrict__ out)
{
    __shared__ char sm[SMEM_BYTES];
    float* s_u = (float*)(sm + OFF_U);
    float* s_x = (float*)(sm + OFF_X);

    const int tid   = threadIdx.x;
    const int wave  = tid >> 6;
    const int lane  = tid & 63;
    const int quad  = lane >> 4;
    const int l15   = lane & 15;
    const int tiles = NXc / Pc;
    const int b     = blockIdx.x / tiles;
    const int i0    = (blockIdx.x % tiles) * Pc;
    const float* ub = u0 + (size_t)b * NXc;
    const float* xb = x  + (size_t)b * NXc;

    // shared wave-role constants for phases C/D/E
    const int mt   = wave & 1;         // point-half (rows rowbase..rowbase+15)
    const int half = wave >> 1;        // C: matrix select; D/E: feature-half
    const int rowbase = mt * 16;

    // ---- cross-barrier PREFETCH of phase C's kt=0 weight fragments ----
    // Independent of everything below; L2 latency hides under phase B (~60us).
    const short8* BmatC = wsv + (half ? (WS_EW2 >> 3) : (WS_NW2 >> 3));
    short8 c_w0 = BmatC[0 * 64 + lane];    // frag (nt=0, kt=0)
    short8 c_w1 = BmatC[4 * 64 + lane];    // frag (nt=1, kt=0)
    short8 c_w2 = BmatC[8 * 64 + lane];    // frag (nt=2, kt=0)
    short8 c_w3 = BmatC[12 * 64 + lane];   // frag (nt=3, kt=0)

    // ---- Phase 0: halo load with clamp ----
    if (tid < HALO) {
        int i = i0 - Kc + tid;
        i = i < 0 ? 0 : (i >= NXc ? NXc - 1 : i);
        s_u[tid] = ub[i];
        s_x[tid] = xb[i];
    }
    __syncthreads();

    // ---- Phase B (fused, packed-native, r5-verified): thread owns dim-quad jq for
    //      4 CONSECUTIVE points; dims as (d0,d1),(d2,d3) float2 pairs.
    //      7-neighbor c-window of 4 points = 10 rows, in registers. ----
    {
        const int jq = tid & 31;           // dim quad 0..31
        const int pbase = (tid >> 5) * 4;  // points pbase..pbase+3
        const int j0 = jq * 4;
        const float4 w0 = *(const float4*)(nw1 + j0);
        const float4 w1 = *(const float4*)(nw1 + DHc + j0);
        const float4 nb = *(const float4*)(nb1 + j0);
        const float4 e0 = *(const float4*)(ew1 + j0);
        const float4 e1 = *(const float4*)(ew1 + DHc + j0);
        const float4 e2 = *(const float4*)(ew1 + 2 * DHc + j0);
        const float4 be = *(const float4*)(eb1 + j0);

        float su[10], sx[10];
        #pragma unroll
        for (int r = 0; r < 10; ++r) {
            su[r] = s_u[pbase + r];        // halo rows pbase-3+Kc .. pbase+6+Kc
            sx[r] = s_x[pbase + r];
        }

        // c_j window as packed pairs: cw01[r]={c[r][0],c[r][1]}, cw23[r]={c[r][2],c[r][3]}
        f32x2 cw01[10], cw23[10];
        #pragma unroll
        for (int r = 0; r < 10; ++r) {
            cw01[r] = pf(SPL(su[r]), (f32x2){e1.x, e1.y}, SPL(sx[r]) * (f32x2){e2.x, e2.y});
            cw23[r] = pf(SPL(su[r]), (f32x2){e1.z, e1.w}, SPL(sx[r]) * (f32x2){e2.z, e2.w});
        }

        #pragma unroll
        for (int r0 = 0; r0 < 4; ++r0) {
            const int p = pbase + r0;
            const float uu = su[r0 + 3], xx = sx[r0 + 3];

            // node MLP first layer + packed poly gelu -> gn (bf16); args bounded ~2.6
            f32x2 n01 = pf(SPL(uu), (f32x2){w0.x, w0.y},
                           pf(SPL(xx), (f32x2){w1.x, w1.y}, (f32x2){nb.x, nb.y}));
            f32x2 n23 = pf(SPL(uu), (f32x2){w0.z, w0.w},
                           pf(SPL(xx), (f32x2){w1.z, w1.w}, (f32x2){nb.z, nb.w}));
            f32x2 g01 = gelu_pk(n01);
            f32x2 g23 = gelu_pk(n23);
            store_bf16x4(sm + OFF_GN + p * RB + j0 * 2, g01.x, g01.y, g23.x, g23.y);

            // edge: a_i = u_i*W0 - x_i*W2 + b1 ; 7-offset packed poly-gelu-sum
            f32x2 a01 = pf(SPL(uu), (f32x2){e0.x, e0.y},
                           pf(SPL(-xx), (f32x2){e2.x, e2.y}, (f32x2){be.x, be.y}));
            f32x2 a23 = pf(SPL(uu), (f32x2){e0.z, e0.w},
                           pf(SPL(-xx), (f32x2){e2.z, e2.w}, (f32x2){be.z, be.w}));
            f32x2 acc01 = SPL(0.f), acc23 = SPL(0.f);
            #pragma unroll
            for (int o = 0; o < Wc; ++o) {
                gelu_pk_acc(a01 + cw01[r0 + o], acc01);
                gelu_pk_acc(a23 + cw23[r0 + o], acc23);
            }
            store_bf16x4(sm + OFF_S + p * RB + j0 * 2, acc01.x, acc01.y, acc23.x, acc23.y);
        }
    }
    __syncthreads();

    // ---- Phase C (MFMA, W as A-operand): D = (act@W)^T -> col=point, rows=4 consecutive features
    //      hcat[:,0:64] = gn@nw2 + nb2 ; hcat[:,64:128] = s@ew2 + 7*eb2
    //      kt=0 weights were prefetched before phase B.
    //      HC aliases GN: barrier between the MFMA reads and the epilogue writes. ----
    short8 d_w0, d_w1, d_w2, d_w3;     // phase-D prefetch, issued inside C
    {
        const int aoff = half ? OFF_S : OFF_GN;
        f32x4 acc[4] = {{0,0,0,0},{0,0,0,0},{0,0,0,0},{0,0,0,0}};
        {   // kt = 0: consume prefetched fragments
            short8 af = *(const short8*)(sm + aoff + (rowbase + l15) * RB + quad * 16);
            acc[0] = __builtin_amdgcn_mfma_f32_16x16x32_bf16(c_w0, af, acc[0], 0, 0, 0);
            acc[1] = __builtin_amdgcn_mfma_f32_16x16x32_bf16(c_w1, af, acc[1], 0, 0, 0);
            acc[2] = __builtin_amdgcn_mfma_f32_16x16x32_bf16(c_w2, af, acc[2], 0, 0, 0);
            acc[3] = __builtin_amdgcn_mfma_f32_16x16x32_bf16(c_w3, af, acc[3], 0, 0, 0);
        }
        #pragma unroll
        for (int kt = 1; kt < 4; ++kt) {
            short8 af = *(const short8*)(sm + aoff + (rowbase + l15) * RB + kt * 64 + quad * 16);
            #pragma unroll
            for (int nt = 0; nt < 4; ++nt) {
                short8 wf = BmatC[(nt * 4 + kt) * 64 + lane];
                acc[nt] = __builtin_amdgcn_mfma_f32_16x16x32_bf16(wf, af, acc[nt], 0, 0, 0);
            }
        }
        // prefetch phase D's kt=0 fragments: fly during epilogue + barrier
        {
            const short8* BmatD = wsv + (WS_CW1 >> 3);
            d_w0 = BmatD[((half * 4 + 0) * 4) * 64 + lane];
            d_w1 = BmatD[((half * 4 + 1) * 4) * 64 + lane];
            d_w2 = BmatD[((half * 4 + 2) * 4) * 64 + lane];
            d_w3 = BmatD[((half * 4 + 3) * 4) * 64 + lane];
        }
        __syncthreads();   // GN/S reads complete before HC overwrites GN space
        const float* bias = half ? eb2 : nb2;
        const float bscale = half ? 7.f : 1.f;
        const int colhalf = half ? DLc : 0;
        const int p = rowbase + l15;          // point this lane owns
        #pragma unroll
        for (int nt = 0; nt < 4; ++nt) {
            float4 bv = ((const float4*)bias)[nt * 4 + quad];   // features nt*16+quad*4 ..+3
            store_bf16x4(sm + OFF_HC + p * RB + (colhalf + nt * 16 + quad * 4) * 2,
                         fmaf(bscale, bv.x, acc[nt][0]),
                         fmaf(bscale, bv.y, acc[nt][1]),
                         fmaf(bscale, bv.z, acc[nt][2]),
                         fmaf(bscale, bv.w, acc[nt][3]));
        }
    }
    __syncthreads();

    // ---- Phase D (MFMA): h2 = gelu(hcat @ cw1 + cb1), feature halves across wave pairs.
    //      kt=0 weights prefetched during phase C.  H2 aliases S. ----
    short8 e_w0, e_w1;                 // phase-E prefetch, issued inside D
    {
        const short8* BmatD = wsv + (WS_CW1 >> 3);
        f32x4 acc[4] = {{0,0,0,0},{0,0,0,0},{0,0,0,0},{0,0,0,0}};
        {   // kt = 0: consume prefetched fragments
            short8 af = *(const short8*)(sm + OFF_HC + (rowbase + l15) * RB + quad * 16);
            acc[0] = __builtin_amdgcn_mfma_f32_16x16x32_bf16(d_w0, af, acc[0], 0, 0, 0);
            acc[1] = __builtin_amdgcn_mfma_f32_16x16x32_bf16(d_w1, af, acc[1], 0, 0, 0);
            acc[2] = __builtin_amdgcn_mfma_f32_16x16x32_bf16(d_w2, af, acc[2], 0, 0, 0);
            acc[3] = __builtin_amdgcn_mfma_f32_16x16x32_bf16(d_w3, af, acc[3], 0, 0, 0);
        }
        #pragma unroll
        for (int kt = 1; kt < 4; ++kt) {
            short8 af = *(const short8*)(sm + OFF_HC + (rowbase + l15) * RB + kt * 64 + quad * 16);
            #pragma unroll
            for (int t = 0; t < 4; ++t) {
                int nt = half * 4 + t;
                short8 wf = BmatD[(nt * 4 + kt) * 64 + lane];
                acc[t] = __builtin_amdgcn_mfma_f32_16x16x32_bf16(wf, af, acc[t], 0, 0, 0);
            }
        }
        // prefetch phase E's kt=0 fragments: fly during gelu epilogue + barrier
        {
            const short8* BmatE = wsv + (WS_CW2 >> 3);
            e_w0 = BmatE[((half * 2 + 0) * 4) * 64 + lane];
            e_w1 = BmatE[((half * 2 + 1) * 4) * 64 + lane];
        }
        const int p = rowbase + l15;
        #pragma unroll
        for (int t = 0; t < 4; ++t) {
            int nbase = (half * 4 + t) * 16 + quad * 4;
            float4 cb = ((const float4*)cb1)[nbase >> 2];
            float h0, h1, h2v, h3;
            gelu2(acc[t][0] + cb.x, acc[t][1] + cb.y, h0, h1);
            gelu2(acc[t][2] + cb.z, acc[t][3] + cb.w, h2v, h3);
            store_bf16x4(sm + OFF_H2 + p * RB + nbase * 2, h0, h1, h2v, h3);
        }
    }
    __syncthreads();

    // ---- Phase E (MFMA): out = h2 @ cw2 + cb2, float4 straight to global.
    //      kt=0 weights prefetched during phase D. ----
    {
        const short8* BmatE = wsv + (WS_CW2 >> 3);
        f32x4 acc[2] = {{0,0,0,0},{0,0,0,0}};
        {   // kt = 0: consume prefetched fragments
            short8 af = *(const short8*)(sm + OFF_H2 + (rowbase + l15) * RB + quad * 16);
            acc[0] = __builtin_amdgcn_mfma_f32_16x16x32_bf16(e_w0, af, acc[0], 0, 0, 0);
            acc[1] = __builtin_amdgcn_mfma_f32_16x16x32_bf16(e_w1, af, acc[1], 0, 0, 0);
        }
        #pragma unroll
        for (int kt = 1; kt < 4; ++kt) {
            short8 af = *(const short8*)(sm + OFF_H2 + (rowbase + l15) * RB + kt * 64 + quad * 16);
            #pragma unroll
            for (int t = 0; t < 2; ++t) {
                int nt = half * 2 + t;
                short8 wf = BmatE[(nt * 4 + kt) * 64 + lane];
                acc[t] = __builtin_amdgcn_mfma_f32_16x16x32_bf16(wf, af, acc[t], 0, 0, 0);
            }
        }
        const int p = rowbase + l15;
        float* outb = out + ((size_t)b * NXc + i0 + p) * DLc;
        #pragma unroll
        for (int t = 0; t < 2; ++t) {
            int nbase = (half * 2 + t) * 16 + quad * 4;
            float4 cb = ((const float4*)cb2)[nbase >> 2];
            float4 v;
            v.x = acc[t][0] + cb.x;
            v.y = acc[t][1] + cb.y;
            v.z = acc[t][2] + cb.z;
            v.w = acc[t][3] + cb.w;
            *(float4*)(outb + nbase) = v;
        }
    }
}

extern "C" void kernel_launch(void* const* d_in, const int* in_sizes, int n_in,
                              void* d_out, int out_size, void* d_ws, size_t ws_size,
                              hipStream_t stream) {
    const float* u0  = (const float*)d_in[0];
    const float* x   = (const float*)d_in[1];
    const float* nw1 = (const float*)d_in[2];
    const float* nb1 = (const float*)d_in[3];
    const float* nw2 = (const float*)d_in[4];
    const float* nb2 = (const float*)d_in[5];
    const float* ew1 = (const float*)d_in[6];
    const float* eb1 = (const float*)d_in[7];
    const float* ew2 = (const float*)d_in[8];
    const float* eb2 = (const float*)d_in[9];
    const float* cw1 = (const float*)d_in[10];
    const float* cb1 = (const float*)d_in[11];
    const float* cw2 = (const float*)d_in[12];
    const float* cb2 = (const float*)d_in[13];
    float* out = (float*)d_out;

    __hip_bfloat16* ws = (__hip_bfloat16*)d_ws;
    pack_weights<<<WS_TOTAL / 256, 256, 0, stream>>>(nw2, ew2, cw1, cw2, ws);

    const int grid = 16 * (NXc / Pc);   // 8192 blocks
    lifting_mfma<<<grid, NTc, 0, stream>>>(u0, x, nw1, nb1, nb2, eb1, eb2, cb1, cb2,
                                           ew1, (const short8*)d_ws, out);
}

// Round 8
// 199.619 us; speedup vs baseline: 1.3217x; 1.3217x over previous
//
#include <hip/hip_runtime.h>
#include <hip/hip_bf16.h>

// Problem constants (fixed by setup_inputs)
#define NXc 16384
#define DHc 128          // d_hidden
#define DLc 64           // d_latent
#define Kc  3            // neighbor radius
#define Wc  7            // 2k+1 offsets
#define Pc  32           // points per block
#define NTc 256          // threads per block
#define HALO 38          // Pc + 2*Kc
#define RB  272          // bf16 activation LDS row stride (128*2 + 16 pad)

typedef __attribute__((ext_vector_type(8))) short short8;   // 8 bf16 = one MFMA A/B fragment
typedef __attribute__((ext_vector_type(4))) float f32x4;    // MFMA accumulator
typedef __attribute__((ext_vector_type(2))) float f32x2;    // packed-fp32 pair

// LDS layout (bytes), double-aliased for 8 blocks/CU:
//   GN,S live B->C (reads).  HC aliases GN (written in C *after* an intra-C barrier).
//   H2 aliases S  (written in D, S dead after C's MFMA reads).
#define OFF_U  0                    // 38 fp32 (pad to 160)
#define OFF_X  160                  // -> 320
#define OFF_GN 320                  // bf16 [32][RB] = 8704 -> 9024
#define OFF_S  9024                 // bf16 [32][RB] = 8704 -> 17728
#define OFF_HC OFF_GN               // alias: written in C after barrier, read in D
#define OFF_H2 OFF_S                // alias: written in D, read in E
#define SMEM_BYTES 17728            // LDS allows 8 blocks/CU (8*17728 = 141824 <= 163840)

// LEDGER of measured facts (final):
// r2: __launch_bounds__(256,8) -> VGPR 32, spill, 252us. (256,6) is spill-free.
// r3: occupancy 6->8 blocks/CU bought only 127->123us => VALU-issue bound, not TLP-starved.
// r4: wholesale asm v_pk_* -> spill (0.78 GB scratch traffic), 234us.
// r5: native float2 poly: clean (VGPR 40, FETCH 5MB), 121us, VALU-busy 89.6us.  <== BEST
// r6: surgical asm v_pk_* Horner (packing FORCED, SGPR coeffs) -> spill again, BUT
//     VALU-busy 90.5us == r5's 89.6 => r5 was already packed; ~90us VALU issue is
//     the gelu-arithmetic floor (deg-8 packed ~= exp2 scalar in issue slots).
// r7: cross-barrier weight prefetch (+16 VGPR liveness across phase B) -> allocator
//     kept VGPR=40 and SPILLED the prefetched quads (FETCH+WRITE 0.65 GB), 189us.
//     Conclusion: ANY added cross-region liveness spills; phase-B pressure defines
//     the allocation edge. Stall slice (~31us) is structurally unreachable from HIP
//     source; ~90us VALU-issue floor at ~74% busy => ~121us is this kernel's ceiling.

// ws layout in bf16 elements. Fragment f=(nt*4+kt), lane l, j:
// element W[kt*32 + (l>>4)*8 + j][nt*16 + (l&15)] at base + f*512 + l*8 + j.
// Used as the MFMA *A* operand => D = (act@W)^T (register-transpose trick).
#define WS_NW2 0        // 128x64
#define WS_EW2 8192     // 128x64
#define WS_CW1 16384    // 128x128
#define WS_CW2 32768    // 128x64
#define WS_TOTAL 40960

#if __has_builtin(__builtin_amdgcn_exp2f)
#define EXP2F(x) __builtin_amdgcn_exp2f(x)
#else
#define EXP2F(x) exp2f(x)
#endif
#if __has_builtin(__builtin_amdgcn_rcpf)
#define RCPF(x) __builtin_amdgcn_rcpf(x)
#else
#define RCPF(x) (1.0f / (x))
#endif

// tanh-form GELU via sigmoid: gelu(x) = x / (1 + exp2(x*(c0 + c1*x^2)))
// Kept ONLY for phase D (args not analytically range-bounded).
#define GC0 -2.30220838f
#define GC1 -0.10294325f

__device__ __forceinline__ void gelu2(float x0, float x1, float& g0, float& g1) {
    x0 = fmaxf(x0, -8.0f);
    x1 = fmaxf(x1, -8.0f);
    float e0 = EXP2F(x0 * fmaf(GC1, x0 * x0, GC0));
    float e1 = EXP2F(x1 * fmaf(GC1, x1 * x1, GC0));
    float t0 = 1.0f + e0, t1 = 1.0f + e1;
    float rr = RCPF(t0 * t1);
    g0 = x0 * t1 * rr;
    g1 = x1 * t0 * rr;
}

// ---- packed exact-GELU polynomial (phase B), NATIVE vector form (r5-verified) ----
// gelu(x) = x*Phi(x); Phi(x) = 0.5 + x*T(z), z = x^2, T even & smooth.
// Degree-8 Newton interpolation of T through EXACT normal-CDF nodes
// x = {0,.5,1,1.5,2,2.5,3,3.25,3.5}; |gelu err| <= ~1e-4 for |x|<=3.5
// (accuracy harness-verified rounds 1/4/5/6/7: absmax identical to exp2 form).
#define PT0 0.39894230f
#define PT1 -0.066489615f
#define PT2 0.0099705784f
#define PT3 -0.0011833764f
#define PT4 1.1289751e-4f
#define PT5 -8.5460760e-6f
#define PT6 4.7818100e-7f
#define PT7 -1.7065000e-8f
#define PT8 2.8231000e-10f

#define SPL(c) ((f32x2){(c), (c)})

__device__ __forceinline__ f32x2 pf(f32x2 a, f32x2 b, f32x2 c) {
#if __has_builtin(__builtin_elementwise_fma)
    return __builtin_elementwise_fma(a, b, c);
#else
    return (f32x2){ fmaf(a.x, b.x, c.x), fmaf(a.y, b.y, c.y) };
#endif
}

// Phi(x) for a packed pair, z supplied by caller.
__device__ __forceinline__ f32x2 phi_pk(f32x2 x, f32x2 z) {
    f32x2 t = pf(SPL(PT8), z, SPL(PT7));
    t = pf(t, z, SPL(PT6));
    t = pf(t, z, SPL(PT5));
    t = pf(t, z, SPL(PT4));
    t = pf(t, z, SPL(PT3));
    t = pf(t, z, SPL(PT2));
    t = pf(t, z, SPL(PT1));
    t = pf(t, z, SPL(PT0));
    return pf(x, t, SPL(0.5f));   // Phi(x)
}
// node gelu: args analytically bounded |x| <= ~2.6 -> no clamp
__device__ __forceinline__ f32x2 gelu_pk(f32x2 x) {
    return x * phi_pk(x, x * x);
}
// edge gelu-accumulate: args bounded |x| <~ 3.4; z-clamp (2 scalar v_min, no packed
// f32 min exists) guards the fast-diverging extrapolation beyond 3.6.
__device__ __forceinline__ void gelu_pk_acc(f32x2 x, f32x2& acc) {
    f32x2 z = x * x;
    z.x = fminf(z.x, 12.96f);
    z.y = fminf(z.y, 12.96f);
    acc = pf(x, phi_pk(x, z), acc);
}

// bf16 pair pack: HW v_cvt_pk_bf16_f32 (gfx950) when available, else branchless RNE.
#if __has_builtin(__builtin_amdgcn_cvt_pk_bf16_f32)
typedef __attribute__((ext_vector_type(2))) __bf16 bf16x2_t;
__device__ __forceinline__ unsigned pack_bf16(float a, float b) {
    bf16x2_t v = __builtin_amdgcn_cvt_pk_bf16_f32(a, b);   // lo = src0, hi = src1
    unsigned r; __builtin_memcpy(&r, &v, 4); return r;
}
#else
__device__ __forceinline__ unsigned bf16rne(float a) {
    unsigned u;
    __builtin_memcpy(&u, &a, 4);
    return u + 0x7FFFu + ((u >> 16) & 1u);
}
__device__ __forceinline__ unsigned pack_bf16(float a, float b) {
    return (bf16rne(a) >> 16) | (bf16rne(b) & 0xFFFF0000u);
}
#endif
__device__ __forceinline__ void store_bf16x4(void* p, float a, float b, float c, float d) {
    uint2 u;
    u.x = pack_bf16(a, b);
    u.y = pack_bf16(c, d);
    *(uint2*)p = u;
}

// ---- prep: fp32 weights -> bf16 MFMA fragments in ws ----
__global__ void pack_weights(const float* __restrict__ nw2, const float* __restrict__ ew2,
                             const float* __restrict__ cw1, const float* __restrict__ cw2,
                             __hip_bfloat16* __restrict__ ws)
{
    int idx = blockIdx.x * 256 + threadIdx.x;     // 0 .. 40959
    const float* src;
    int N, base, e;
    if (idx < 8192)       { src = nw2; N = 64;  base = WS_NW2; e = idx; }
    else if (idx < 16384) { src = ew2; N = 64;  base = WS_EW2; e = idx - 8192; }
    else if (idx < 32768) { src = cw1; N = 128; base = WS_CW1; e = idx - 16384; }
    else                  { src = cw2; N = 64;  base = WS_CW2; e = idx - 32768; }
    int f = e >> 9, l = (e >> 3) & 63, j = e & 7;
    int nt = f >> 2, kt = f & 3;
    int k = kt * 32 + (l >> 4) * 8 + j;
    int n = nt * 16 + (l & 15);
    ws[base + e] = __float2bfloat16(src[k * N + n]);
}

__global__ __launch_bounds__(NTc, 6)
void lifting_mfma(const float* __restrict__ u0, const float* __restrict__ x,
                  const float* __restrict__ nw1, const float* __restrict__ nb1,
                  const float* __restrict__ nb2, const float* __restrict__ eb1,
                  const float* __restrict__ eb2, const float* __restrict__ cb1,
                  const float* __restrict__ cb2, const float* __restrict__ ew1,
                  const short8* __restrict__ wsv, float* __restrict__ out)
{
    __shared__ char sm[SMEM_BYTES];
    float* s_u = (float*)(sm + OFF_U);
    float* s_x = (float*)(sm + OFF_X);

    const int tid   = threadIdx.x;
    const int wave  = tid >> 6;
    const int lane  = tid & 63;
    const int quad  = lane >> 4;
    const int l15   = lane & 15;
    const int tiles = NXc / Pc;
    const int b     = blockIdx.x / tiles;
    const int i0    = (blockIdx.x % tiles) * Pc;
    const float* ub = u0 + (size_t)b * NXc;
    const float* xb = x  + (size_t)b * NXc;

    // ---- Phase 0: halo load with clamp ----
    if (tid < HALO) {
        int i = i0 - Kc + tid;
        i = i < 0 ? 0 : (i >= NXc ? NXc - 1 : i);
        s_u[tid] = ub[i];
        s_x[tid] = xb[i];
    }
    __syncthreads();

    // ---- Phase B (fused, packed-native): thread owns dim-quad jq for 4 CONSECUTIVE
    //      points; dims as (d0,d1),(d2,d3) float2 pairs -> v_pk_* ops.
    //      7-neighbor c-window of 4 points = 10 rows, in registers (compiler may
    //      rematerialize from LDS -- that freedom is what keeps VGPR at 40). ----
    {
        const int jq = tid & 31;           // dim quad 0..31
        const int pbase = (tid >> 5) * 4;  // points pbase..pbase+3
        const int j0 = jq * 4;
        const float4 w0 = *(const float4*)(nw1 + j0);
        const float4 w1 = *(const float4*)(nw1 + DHc + j0);
        const float4 nb = *(const float4*)(nb1 + j0);
        const float4 e0 = *(const float4*)(ew1 + j0);
        const float4 e1 = *(const float4*)(ew1 + DHc + j0);
        const float4 e2 = *(const float4*)(ew1 + 2 * DHc + j0);
        const float4 be = *(const float4*)(eb1 + j0);

        float su[10], sx[10];
        #pragma unroll
        for (int r = 0; r < 10; ++r) {
            su[r] = s_u[pbase + r];        // halo rows pbase-3+Kc .. pbase+6+Kc
            sx[r] = s_x[pbase + r];
        }

        // c_j window as packed pairs: cw01[r]={c[r][0],c[r][1]}, cw23[r]={c[r][2],c[r][3]}
        f32x2 cw01[10], cw23[10];
        #pragma unroll
        for (int r = 0; r < 10; ++r) {
            cw01[r] = pf(SPL(su[r]), (f32x2){e1.x, e1.y}, SPL(sx[r]) * (f32x2){e2.x, e2.y});
            cw23[r] = pf(SPL(su[r]), (f32x2){e1.z, e1.w}, SPL(sx[r]) * (f32x2){e2.z, e2.w});
        }

        #pragma unroll
        for (int r0 = 0; r0 < 4; ++r0) {
            const int p = pbase + r0;
            const float uu = su[r0 + 3], xx = sx[r0 + 3];

            // node MLP first layer + packed poly gelu -> gn (bf16); args bounded ~2.6
            f32x2 n01 = pf(SPL(uu), (f32x2){w0.x, w0.y},
                           pf(SPL(xx), (f32x2){w1.x, w1.y}, (f32x2){nb.x, nb.y}));
            f32x2 n23 = pf(SPL(uu), (f32x2){w0.z, w0.w},
                           pf(SPL(xx), (f32x2){w1.z, w1.w}, (f32x2){nb.z, nb.w}));
            f32x2 g01 = gelu_pk(n01);
            f32x2 g23 = gelu_pk(n23);
            store_bf16x4(sm + OFF_GN + p * RB + j0 * 2, g01.x, g01.y, g23.x, g23.y);

            // edge: a_i = u_i*W0 - x_i*W2 + b1 ; 7-offset packed poly-gelu-sum
            f32x2 a01 = pf(SPL(uu), (f32x2){e0.x, e0.y},
                           pf(SPL(-xx), (f32x2){e2.x, e2.y}, (f32x2){be.x, be.y}));
            f32x2 a23 = pf(SPL(uu), (f32x2){e0.z, e0.w},
                           pf(SPL(-xx), (f32x2){e2.z, e2.w}, (f32x2){be.z, be.w}));
            f32x2 acc01 = SPL(0.f), acc23 = SPL(0.f);
            #pragma unroll
            for (int o = 0; o < Wc; ++o) {
                gelu_pk_acc(a01 + cw01[r0 + o], acc01);
                gelu_pk_acc(a23 + cw23[r0 + o], acc23);
            }
            store_bf16x4(sm + OFF_S + p * RB + j0 * 2, acc01.x, acc01.y, acc23.x, acc23.y);
        }
    }
    __syncthreads();

    // ---- Phase C (MFMA, W as A-operand): D = (act@W)^T -> col=point, rows=4 consecutive features
    //      hcat[:,0:64] = gn@nw2 + nb2 ; hcat[:,64:128] = s@ew2 + 7*eb2
    //      HC aliases GN: barrier between the MFMA reads and the epilogue writes. ----
    {
        const int mt = wave & 1, mat = wave >> 1;
        const int rowbase = mt * 16;
        const int aoff = mat ? OFF_S : OFF_GN;
        const short8* Bmat = wsv + (mat ? (WS_EW2 >> 3) : (WS_NW2 >> 3));
        f32x4 acc[4] = {{0,0,0,0},{0,0,0,0},{0,0,0,0},{0,0,0,0}};
        #pragma unroll
        for (int kt = 0; kt < 4; ++kt) {
            short8 af = *(const short8*)(sm + aoff + (rowbase + l15) * RB + kt * 64 + quad * 16);
            #pragma unroll
            for (int nt = 0; nt < 4; ++nt) {
                short8 wf = Bmat[(nt * 4 + kt) * 64 + lane];
                acc[nt] = __builtin_amdgcn_mfma_f32_16x16x32_bf16(wf, af, acc[nt], 0, 0, 0);
            }
        }
        __syncthreads();   // GN/S reads complete before HC overwrites GN space
        const float* bias = mat ? eb2 : nb2;
        const float bscale = mat ? 7.f : 1.f;
        const int colhalf = mat ? DLc : 0;
        const int p = rowbase + l15;          // point this lane owns
        #pragma unroll
        for (int nt = 0; nt < 4; ++nt) {
            float4 bv = ((const float4*)bias)[nt * 4 + quad];   // features nt*16+quad*4 ..+3
            store_bf16x4(sm + OFF_HC + p * RB + (colhalf + nt * 16 + quad * 4) * 2,
                         fmaf(bscale, bv.x, acc[nt][0]),
                         fmaf(bscale, bv.y, acc[nt][1]),
                         fmaf(bscale, bv.z, acc[nt][2]),
                         fmaf(bscale, bv.w, acc[nt][3]));
        }
    }
    __syncthreads();

    // ---- Phase D (MFMA): h2 = gelu(hcat @ cw1 + cb1), feature halves across wave pairs.
    //      H2 aliases S (S dead after phase C's MFMA reads). ----
    {
        const int mt = wave & 1, nh = wave >> 1;
        const int rowbase = mt * 16;
        const short8* Bmat = wsv + (WS_CW1 >> 3);
        f32x4 acc[4] = {{0,0,0,0},{0,0,0,0},{0,0,0,0},{0,0,0,0}};
        #pragma unroll
        for (int kt = 0; kt < 4; ++kt) {
            short8 af = *(const short8*)(sm + OFF_HC + (rowbase + l15) * RB + kt * 64 + quad * 16);
            #pragma unroll
            for (int t = 0; t < 4; ++t) {
                int nt = nh * 4 + t;
                short8 wf = Bmat[(nt * 4 + kt) * 64 + lane];
                acc[t] = __builtin_amdgcn_mfma_f32_16x16x32_bf16(wf, af, acc[t], 0, 0, 0);
            }
        }
        const int p = rowbase + l15;
        #pragma unroll
        for (int t = 0; t < 4; ++t) {
            int nbase = (nh * 4 + t) * 16 + quad * 4;
            float4 cb = ((const float4*)cb1)[nbase >> 2];
            float h0, h1, h2v, h3;
            gelu2(acc[t][0] + cb.x, acc[t][1] + cb.y, h0, h1);
            gelu2(acc[t][2] + cb.z, acc[t][3] + cb.w, h2v, h3);
            store_bf16x4(sm + OFF_H2 + p * RB + nbase * 2, h0, h1, h2v, h3);
        }
    }
    __syncthreads();

    // ---- Phase E (MFMA): out = h2 @ cw2 + cb2, float4 straight to global ----
    {
        const int mt = wave & 1, nh = wave >> 1;
        const int rowbase = mt * 16;
        const short8* Bmat = wsv + (WS_CW2 >> 3);
        f32x4 acc[2] = {{0,0,0,0},{0,0,0,0}};
        #pragma unroll
        for (int kt = 0; kt < 4; ++kt) {
            short8 af = *(const short8*)(sm + OFF_H2 + (rowbase + l15) * RB + kt * 64 + quad * 16);
            #pragma unroll
            for (int t = 0; t < 2; ++t) {
                int nt = nh * 2 + t;
                short8 wf = Bmat[(nt * 4 + kt) * 64 + lane];
                acc[t] = __builtin_amdgcn_mfma_f32_16x16x32_bf16(wf, af, acc[t], 0, 0, 0);
            }
        }
        const int p = rowbase + l15;
        float* outb = out + ((size_t)b * NXc + i0 + p) * DLc;
        #pragma unroll
        for (int t = 0; t < 2; ++t) {
            int nbase = (nh * 2 + t) * 16 + quad * 4;
            float4 cb = ((const float4*)cb2)[nbase >> 2];
            float4 v;
            v.x = acc[t][0] + cb.x;
            v.y = acc[t][1] + cb.y;
            v.z = acc[t][2] + cb.z;
            v.w = acc[t][3] + cb.w;
            *(float4*)(outb + nbase) = v;
        }
    }
}

extern "C" void kernel_launch(void* const* d_in, const int* in_sizes, int n_in,
                              void* d_out, int out_size, void* d_ws, size_t ws_size,
                              hipStream_t stream) {
    const float* u0  = (const float*)d_in[0];
    const float* x   = (const float*)d_in[1];
    const float* nw1 = (const float*)d_in[2];
    const float* nb1 = (const float*)d_in[3];
    const float* nw2 = (const float*)d_in[4];
    const float* nb2 = (const float*)d_in[5];
    const float* ew1 = (const float*)d_in[6];
    const float* eb1 = (const float*)d_in[7];
    const float* ew2 = (const float*)d_in[8];
    const float* eb2 = (const float*)d_in[9];
    const float* cw1 = (const float*)d_in[10];
    const float* cb1 = (const float*)d_in[11];
    const float* cw2 = (const float*)d_in[12];
    const float* cb2 = (const float*)d_in[13];
    float* out = (float*)d_out;

    __hip_bfloat16* ws = (__hip_bfloat16*)d_ws;
    pack_weights<<<WS_TOTAL / 256, 256, 0, stream>>>(nw2, ew2, cw1, cw2, ws);

    const int grid = 16 * (NXc / Pc);   // 8192 blocks
    lifting_mfma<<<grid, NTc, 0, stream>>>(u0, x, nw1, nb1, nb2, eb1, eb2, cb1, cb2,
                                           ew1, (const short8*)d_ws, out);
}